// Round 2
// baseline (1262.244 us; speedup 1.0000x reference)
//
#include <hip/hip_runtime.h>
#include <math.h>

// PDELayer: 100 steps of u <- u + alpha(row)*u_xx + beta(col)*u_yy, 48x48
// interior with a FROZEN reflect-pad ring.
//
// R7: packed-fp32 rewrite. Evidence from R5/R6 counters: VOP3P f16 executes
// at ~4 cyc/wave64 (VALUBusy 77-85% with ~4.7 cyc/instr effective), i.e.
// pk-f16 gives NO flop-rate advantage over f32 FMA. MI355X's 157.3 TF fp32
// spec implies v_pk_fma_f32 at full 2-cyc rate = 2x our measured rate.
// So: pack 2 IMAGES per VGPR-pair as <2 x float>, same instruction schedule.
// Register pressure (f32 state doubles) is handled by splitting each
// image-pair across 2 waves (6 rows/lane, 24 rows/wave, 8192 waves total);
// the seam row is exchanged via a tiny double-buffered LDS strip with one
// __syncthreads per step. __launch_bounds__(256,4) pins VGPR <= 128 so
// 4 waves/SIMD stay resident.
// Math per cell (5 pk-ops): n = a*s1 + b*s2 + cc*x (+ e_edge),
// cc = 1-2a-2b, frozen L/R pads folded into e0/e2. All fp32 -> absmax ~1e-5.

#define NTSTEPS 100

typedef float v2f __attribute__((ext_vector_type(2)));
typedef int   v2i __attribute__((ext_vector_type(2)));

__device__ __forceinline__ v2f splat2(float x) { v2f r; r.x = x; r.y = x; return r; }

__device__ __forceinline__ v2f dpp_shr1_z(v2f v) {
    // lane tx receives lane tx-1 within its 16-lane row; tx==0 gets 0
    v2i xi = __builtin_bit_cast(v2i, v);
    v2i r;
    r.x = __builtin_amdgcn_update_dpp(0, xi.x, 0x111, 0xF, 0xF, true);
    r.y = __builtin_amdgcn_update_dpp(0, xi.y, 0x111, 0xF, 0xF, true);
    return __builtin_bit_cast(v2f, r);
}
__device__ __forceinline__ v2f dpp_shl1_z(v2f v) {
    // lane tx receives lane tx+1 within its 16-lane row; tx==15 gets 0
    v2i xi = __builtin_bit_cast(v2i, v);
    v2i r;
    r.x = __builtin_amdgcn_update_dpp(0, xi.x, 0x101, 0xF, 0xF, true);
    r.y = __builtin_amdgcn_update_dpp(0, xi.y, 0x101, 0xF, 0xF, true);
    return __builtin_bit_cast(v2f, r);
}
__device__ __forceinline__ v2f bperm2(int addr, v2f v) {
    v2i xi = __builtin_bit_cast(v2i, v);
    v2i r;
    r.x = __builtin_amdgcn_ds_bpermute(addr, xi.x);
    r.y = __builtin_amdgcn_ds_bpermute(addr, xi.y);
    return __builtin_bit_cast(v2f, r);
}
__device__ __forceinline__ v2f pkfma(v2f a, v2f b, v2f c) {
    return __builtin_elementwise_fma(a, b, c);
}

// ws[0..47] = alpha per row, ws[48..95] = beta per col (unmasked fp32 tables)
__global__ void coeff_kernel(
    const float* __restrict__ pa1, const float* __restrict__ pa2,
    const float* __restrict__ pa3, const float* __restrict__ pb1,
    const float* __restrict__ pb2, const float* __restrict__ pb3,
    float* __restrict__ ws)
{
    int tid = threadIdx.x;
    if (tid < 48) {
        float a1 = fabsf(pa1[0]), a2 = fabsf(pa2[0]), a3 = fabsf(pa3[0]);
        float b1 = fabsf(pb1[0]), b2 = fabsf(pb2[0]), b3 = fabsf(pb3[0]);
        float t = 6.283185307179586f * ((float)tid / 47.0f);
        float s = sinf(t), c = cosf(t);
        ws[tid]      = 0.1152f * (a1 + a2 * s + a3 * c);  // 0.5*DT/DX^2
        ws[48 + tid] = 0.2304f * (b1 + b2 * c + b3 * s);  // DT/DY^2
    }
}

__global__ __launch_bounds__(256, 4) void pde_kernel(
    const float* __restrict__ u0,
    const float* __restrict__ cw,
    float* __restrict__ out)
{
    // seam/frozen exchange strip: [buf][pairInBlock][specialRow][col]
    // specialRow: 0 = half0-top (frozen), 1 = half1-top (seam, row 23),
    //             2 = half0-bottom (seam, row 24), 3 = half1-bottom (frozen)
    __shared__ v2f lds[2][2][4][48];

    const int tid  = threadIdx.x;
    const int lane = tid & 63;
    const int wv   = tid >> 6;
    const int pib  = wv >> 1;              // image-pair within block
    const int half = wv & 1;               // 0: rows 0..23, 1: rows 24..47
    const int pair = blockIdx.x * 2 + pib; // global image-pair index
    const int tx   = lane & 15;
    const int ty   = lane >> 4;
    const int c0   = 3 * tx;
    const int g0   = half * 24 + ty * 6;   // first global row owned by lane

    const float* __restrict__ srcA = u0 + (size_t)(2 * pair) * 2304;
    const float* __restrict__ srcB = srcA + 2304;

    // ---- coefficients (scalar f32; splatted at use) ----
    const float bf0 = cw[48 + c0 + 0];
    const float bf1 = cw[48 + c0 + 1];
    const float bf2 = cw[48 + c0 + 2];
    float af[6], cf[6][3];
    #pragma unroll
    for (int k = 0; k < 6; ++k) {
        float av = cw[g0 + k];
        af[k] = av;
        cf[k][0] = 1.0f - 2.0f * av - 2.0f * bf0;
        cf[k][1] = 1.0f - 2.0f * av - 2.0f * bf1;
        cf[k][2] = 1.0f - 2.0f * av - 2.0f * bf2;
    }

    // ---- state + frozen edge-pad constants ----
    v2f u[6][3];
    v2f e0[6], e2[6];     // b0*leftpad (tx==0) / b2*rightpad (tx==15), else 0
    v2f tH[3], bH[3];     // vertical halos (valid for current OLD state)

    const v2f vz = splat2(0.0f);
    const int epc = (tx == 15) ? 46 : 1;   // frozen pad source column
    #pragma unroll
    for (int k = 0; k < 6; ++k) {
        #pragma unroll
        for (int c = 0; c < 3; ++c) {
            int o = (g0 + k) * 48 + c0 + c;
            v2f v; v.x = srcA[o]; v.y = srcB[o];
            u[k][c] = v;
        }
        int oe = (g0 + k) * 48 + epc;
        float eA = srcA[oe], eB = srcB[oe];
        v2f el; el.x = bf0 * eA; el.y = bf0 * eB;
        v2f er; er.x = bf2 * eA; er.y = bf2 * eB;
        e0[k] = (tx == 0)  ? el : vz;
        e2[k] = (tx == 15) ? er : vz;
    }
    {
        const int tor = (g0 == 0) ? 1 : (g0 - 1);          // reflect at top
        const int gb  = g0 + 5;
        const int bor = (gb == 47) ? 46 : (gb + 1);        // reflect at bottom
        #pragma unroll
        for (int c = 0; c < 3; ++c) {
            int ot = tor * 48 + c0 + c, ob = bor * 48 + c0 + c;
            v2f vt; vt.x = srcA[ot]; vt.y = srcB[ot];
            v2f vb; vb.x = srcA[ob]; vb.y = srcB[ob];
            tH[c] = vt;
            bH[c] = vb;
        }
    }

    // ---- prewrite frozen special rows into BOTH buffers ----
    if (half == 0 && ty == 0) {
        #pragma unroll
        for (int c = 0; c < 3; ++c) {
            lds[0][pib][0][c0 + c] = tH[c];
            lds[1][pib][0][c0 + c] = tH[c];
        }
    }
    if (half == 1 && ty == 3) {
        #pragma unroll
        for (int c = 0; c < 3; ++c) {
            lds[0][pib][3][c0 + c] = bH[c];
            lds[1][pib][3][c0 + c] = bH[c];
        }
    }

    const int upA = ((lane - 16) & 63) << 2;
    const int dnA = ((lane + 16) & 63) << 2;
    const int topRow = half;        // 0 -> frozen row0, 1 -> seam row1
    const int botRow = 2 + half;    // 0 -> seam row2,  1 -> frozen row3
    const bool isTopTy = (ty == 0);
    const bool isBotTy = (ty == 3);

    #pragma unroll 1
    for (int t = 0; t < NTSTEPS; ++t) {
        // ---- update 6 rows (ascending, carrying old row-above) ----
        v2f p0 = tH[0], p1 = tH[1], p2 = tH[2];
        #pragma unroll
        for (int k = 0; k < 6; ++k) {
            const v2f x0 = u[k][0], x1 = u[k][1], x2 = u[k][2];
            const v2f hl = dpp_shr1_z(x2);
            const v2f hr = dpp_shl1_z(x0);
            const v2f d0 = (k == 5) ? bH[0] : u[k + 1][0];
            const v2f d1 = (k == 5) ? bH[1] : u[k + 1][1];
            const v2f d2 = (k == 5) ? bH[2] : u[k + 1][2];
            const v2f s10 = p0 + d0;
            const v2f s11 = p1 + d1;
            const v2f s12 = p2 + d2;
            const v2f s20 = hl + x1;
            const v2f s21 = x0 + x2;
            const v2f s22 = x1 + hr;
            const v2f ak = splat2(af[k]);
            u[k][0] = pkfma(ak, s10, pkfma(splat2(bf0), s20,
                        pkfma(splat2(cf[k][0]), x0, e0[k])));
            u[k][1] = pkfma(ak, s11, pkfma(splat2(bf1), s21,
                        splat2(cf[k][1]) * x1));
            u[k][2] = pkfma(ak, s12, pkfma(splat2(bf2), s22,
                        pkfma(splat2(cf[k][2]), x2, e2[k])));
            p0 = x0; p1 = x1; p2 = x2;
        }

        // ---- halo exchange for next step (on NEW state) ----
        if (t + 1 < NTSTEPS) {
            const int bq = t & 1;
            // intra-wave vertical halos
            const v2f tv0 = bperm2(upA, u[5][0]);
            const v2f tv1 = bperm2(upA, u[5][1]);
            const v2f tv2 = bperm2(upA, u[5][2]);
            const v2f bv0 = bperm2(dnA, u[0][0]);
            const v2f bv1 = bperm2(dnA, u[0][1]);
            const v2f bv2 = bperm2(dnA, u[0][2]);
            // seam rows cross waves through LDS
            if (half == 0 && isBotTy) {         // new row 23 -> half1's top
                lds[bq][pib][1][c0 + 0] = u[5][0];
                lds[bq][pib][1][c0 + 1] = u[5][1];
                lds[bq][pib][1][c0 + 2] = u[5][2];
            }
            if (half == 1 && isTopTy) {         // new row 24 -> half0's bottom
                lds[bq][pib][2][c0 + 0] = u[0][0];
                lds[bq][pib][2][c0 + 1] = u[0][1];
                lds[bq][pib][2][c0 + 2] = u[0][2];
            }
            __syncthreads();
            v2f sT0, sT1, sT2, sB0, sB1, sB2;
            if (isTopTy) {
                sT0 = lds[bq][pib][topRow][c0 + 0];
                sT1 = lds[bq][pib][topRow][c0 + 1];
                sT2 = lds[bq][pib][topRow][c0 + 2];
            }
            if (isBotTy) {
                sB0 = lds[bq][pib][botRow][c0 + 0];
                sB1 = lds[bq][pib][botRow][c0 + 1];
                sB2 = lds[bq][pib][botRow][c0 + 2];
            }
            tH[0] = isTopTy ? sT0 : tv0;
            tH[1] = isTopTy ? sT1 : tv1;
            tH[2] = isTopTy ? sT2 : tv2;
            bH[0] = isBotTy ? sB0 : bv0;
            bH[1] = isBotTy ? sB1 : bv1;
            bH[2] = isBotTy ? sB2 : bv2;
        }
    }

    float* __restrict__ dstA = out + (size_t)(2 * pair) * 2304;
    float* __restrict__ dstB = dstA + 2304;
    #pragma unroll
    for (int k = 0; k < 6; ++k) {
        #pragma unroll
        for (int c = 0; c < 3; ++c) {
            int o = (g0 + k) * 48 + c0 + c;
            dstA[o] = u[k][c].x;
            dstB[o] = u[k][c].y;
        }
    }
}

extern "C" void kernel_launch(void* const* d_in, const int* in_sizes, int n_in,
                              void* d_out, int out_size, void* d_ws, size_t ws_size,
                              hipStream_t stream) {
    const float* u0 = (const float*)d_in[0];
    float* ws = (float*)d_ws;
    coeff_kernel<<<1, 64, 0, stream>>>(
        (const float*)d_in[1], (const float*)d_in[2], (const float*)d_in[3],
        (const float*)d_in[4], (const float*)d_in[5], (const float*)d_in[6],
        ws);
    pde_kernel<<<2048, 256, 0, stream>>>(u0, ws, (float*)d_out);
}

// Round 4
// 414.607 us; speedup vs baseline: 3.0444x; 3.0444x over previous
//
#include <hip/hip_runtime.h>
#include <math.h>

// PDELayer: 100 steps of u <- u + alpha(row)*u_xx + beta(col)*u_yy, 48x48
// interior with a FROZEN reflect-pad ring.
//
// R8 (resubmit; R8 bench was lost to GPUAcquisitionTimeout): identical
// structure to R7 (packed-fp32, 2 images per VGPR-pair, image-pair split
// across 2 waves, 6 rows/lane, LDS seam exchange), but
// __launch_bounds__(256, 2) instead of (256, 4).
// R7 post-mortem: the (256,4) cap (128 VGPR) starved the allocator -> it
// allocated 64 VGPRs and spilled the state arrays to scratch: FETCH_SIZE
// 40 MB -> 3.39 GB, VALUBusy 85% -> 17%, dur 227 -> 1190 us. The kernel
// needs ~150 VGPRs live (36 state + 24 edge consts + 12 halos + 27 coeff
// + bperm temps). Cap 256 -> no spill, 2 waves/SIMD resident; R6 showed
// 77% VALUBusy at 1.6 waves/SIMD, so residency is sufficient.
// Math per cell (5 pk-ops): n = a*s1 + b*s2 + cc*x (+ e_edge),
// cc = 1-2a-2b, frozen L/R pads folded into e0/e2. All fp32.

#define NTSTEPS 100

typedef float v2f __attribute__((ext_vector_type(2)));
typedef int   v2i __attribute__((ext_vector_type(2)));

__device__ __forceinline__ v2f splat2(float x) { v2f r; r.x = x; r.y = x; return r; }

__device__ __forceinline__ v2f dpp_shr1_z(v2f v) {
    // lane tx receives lane tx-1 within its 16-lane row; tx==0 gets 0
    v2i xi = __builtin_bit_cast(v2i, v);
    v2i r;
    r.x = __builtin_amdgcn_update_dpp(0, xi.x, 0x111, 0xF, 0xF, true);
    r.y = __builtin_amdgcn_update_dpp(0, xi.y, 0x111, 0xF, 0xF, true);
    return __builtin_bit_cast(v2f, r);
}
__device__ __forceinline__ v2f dpp_shl1_z(v2f v) {
    // lane tx receives lane tx+1 within its 16-lane row; tx==15 gets 0
    v2i xi = __builtin_bit_cast(v2i, v);
    v2i r;
    r.x = __builtin_amdgcn_update_dpp(0, xi.x, 0x101, 0xF, 0xF, true);
    r.y = __builtin_amdgcn_update_dpp(0, xi.y, 0x101, 0xF, 0xF, true);
    return __builtin_bit_cast(v2f, r);
}
__device__ __forceinline__ v2f bperm2(int addr, v2f v) {
    v2i xi = __builtin_bit_cast(v2i, v);
    v2i r;
    r.x = __builtin_amdgcn_ds_bpermute(addr, xi.x);
    r.y = __builtin_amdgcn_ds_bpermute(addr, xi.y);
    return __builtin_bit_cast(v2f, r);
}
__device__ __forceinline__ v2f pkfma(v2f a, v2f b, v2f c) {
    return __builtin_elementwise_fma(a, b, c);
}

// ws[0..47] = alpha per row, ws[48..95] = beta per col (unmasked fp32 tables)
__global__ void coeff_kernel(
    const float* __restrict__ pa1, const float* __restrict__ pa2,
    const float* __restrict__ pa3, const float* __restrict__ pb1,
    const float* __restrict__ pb2, const float* __restrict__ pb3,
    float* __restrict__ ws)
{
    int tid = threadIdx.x;
    if (tid < 48) {
        float a1 = fabsf(pa1[0]), a2 = fabsf(pa2[0]), a3 = fabsf(pa3[0]);
        float b1 = fabsf(pb1[0]), b2 = fabsf(pb2[0]), b3 = fabsf(pb3[0]);
        float t = 6.283185307179586f * ((float)tid / 47.0f);
        float s = sinf(t), c = cosf(t);
        ws[tid]      = 0.1152f * (a1 + a2 * s + a3 * c);  // 0.5*DT/DX^2
        ws[48 + tid] = 0.2304f * (b1 + b2 * c + b3 * s);  // DT/DY^2
    }
}

__global__ __launch_bounds__(256, 2) void pde_kernel(
    const float* __restrict__ u0,
    const float* __restrict__ cw,
    float* __restrict__ out)
{
    // seam/frozen exchange strip: [buf][pairInBlock][specialRow][col]
    // specialRow: 0 = half0-top (frozen), 1 = half1-top (seam, row 23),
    //             2 = half0-bottom (seam, row 24), 3 = half1-bottom (frozen)
    __shared__ v2f lds[2][2][4][48];

    const int tid  = threadIdx.x;
    const int lane = tid & 63;
    const int wv   = tid >> 6;
    const int pib  = wv >> 1;              // image-pair within block
    const int half = wv & 1;               // 0: rows 0..23, 1: rows 24..47
    const int pair = blockIdx.x * 2 + pib; // global image-pair index
    const int tx   = lane & 15;
    const int ty   = lane >> 4;
    const int c0   = 3 * tx;
    const int g0   = half * 24 + ty * 6;   // first global row owned by lane

    const float* __restrict__ srcA = u0 + (size_t)(2 * pair) * 2304;
    const float* __restrict__ srcB = srcA + 2304;

    // ---- coefficients (scalar f32; splatted at use) ----
    const float bf0 = cw[48 + c0 + 0];
    const float bf1 = cw[48 + c0 + 1];
    const float bf2 = cw[48 + c0 + 2];
    float af[6], cf[6][3];
    #pragma unroll
    for (int k = 0; k < 6; ++k) {
        float av = cw[g0 + k];
        af[k] = av;
        cf[k][0] = 1.0f - 2.0f * av - 2.0f * bf0;
        cf[k][1] = 1.0f - 2.0f * av - 2.0f * bf1;
        cf[k][2] = 1.0f - 2.0f * av - 2.0f * bf2;
    }

    // ---- state + frozen edge-pad constants ----
    v2f u[6][3];
    v2f e0[6], e2[6];     // b0*leftpad (tx==0) / b2*rightpad (tx==15), else 0
    v2f tH[3], bH[3];     // vertical halos (valid for current OLD state)

    const v2f vz = splat2(0.0f);
    const int epc = (tx == 15) ? 46 : 1;   // frozen pad source column
    #pragma unroll
    for (int k = 0; k < 6; ++k) {
        #pragma unroll
        for (int c = 0; c < 3; ++c) {
            int o = (g0 + k) * 48 + c0 + c;
            v2f v; v.x = srcA[o]; v.y = srcB[o];
            u[k][c] = v;
        }
        int oe = (g0 + k) * 48 + epc;
        float eA = srcA[oe], eB = srcB[oe];
        v2f el; el.x = bf0 * eA; el.y = bf0 * eB;
        v2f er; er.x = bf2 * eA; er.y = bf2 * eB;
        e0[k] = (tx == 0)  ? el : vz;
        e2[k] = (tx == 15) ? er : vz;
    }
    {
        const int tor = (g0 == 0) ? 1 : (g0 - 1);          // reflect at top
        const int gb  = g0 + 5;
        const int bor = (gb == 47) ? 46 : (gb + 1);        // reflect at bottom
        #pragma unroll
        for (int c = 0; c < 3; ++c) {
            int ot = tor * 48 + c0 + c, ob = bor * 48 + c0 + c;
            v2f vt; vt.x = srcA[ot]; vt.y = srcB[ot];
            v2f vb; vb.x = srcA[ob]; vb.y = srcB[ob];
            tH[c] = vt;
            bH[c] = vb;
        }
    }

    // ---- prewrite frozen special rows into BOTH buffers ----
    if (half == 0 && ty == 0) {
        #pragma unroll
        for (int c = 0; c < 3; ++c) {
            lds[0][pib][0][c0 + c] = tH[c];
            lds[1][pib][0][c0 + c] = tH[c];
        }
    }
    if (half == 1 && ty == 3) {
        #pragma unroll
        for (int c = 0; c < 3; ++c) {
            lds[0][pib][3][c0 + c] = bH[c];
            lds[1][pib][3][c0 + c] = bH[c];
        }
    }

    const int upA = ((lane - 16) & 63) << 2;
    const int dnA = ((lane + 16) & 63) << 2;
    const int topRow = half;        // 0 -> frozen row0, 1 -> seam row1
    const int botRow = 2 + half;    // 0 -> seam row2,  1 -> frozen row3
    const bool isTopTy = (ty == 0);
    const bool isBotTy = (ty == 3);

    #pragma unroll 1
    for (int t = 0; t < NTSTEPS; ++t) {
        // ---- update 6 rows (ascending, carrying old row-above) ----
        v2f p0 = tH[0], p1 = tH[1], p2 = tH[2];
        #pragma unroll
        for (int k = 0; k < 6; ++k) {
            const v2f x0 = u[k][0], x1 = u[k][1], x2 = u[k][2];
            const v2f hl = dpp_shr1_z(x2);
            const v2f hr = dpp_shl1_z(x0);
            const v2f d0 = (k == 5) ? bH[0] : u[k + 1][0];
            const v2f d1 = (k == 5) ? bH[1] : u[k + 1][1];
            const v2f d2 = (k == 5) ? bH[2] : u[k + 1][2];
            const v2f s10 = p0 + d0;
            const v2f s11 = p1 + d1;
            const v2f s12 = p2 + d2;
            const v2f s20 = hl + x1;
            const v2f s21 = x0 + x2;
            const v2f s22 = x1 + hr;
            const v2f ak = splat2(af[k]);
            u[k][0] = pkfma(ak, s10, pkfma(splat2(bf0), s20,
                        pkfma(splat2(cf[k][0]), x0, e0[k])));
            u[k][1] = pkfma(ak, s11, pkfma(splat2(bf1), s21,
                        splat2(cf[k][1]) * x1));
            u[k][2] = pkfma(ak, s12, pkfma(splat2(bf2), s22,
                        pkfma(splat2(cf[k][2]), x2, e2[k])));
            p0 = x0; p1 = x1; p2 = x2;
        }

        // ---- halo exchange for next step (on NEW state) ----
        if (t + 1 < NTSTEPS) {
            const int bq = t & 1;
            // intra-wave vertical halos
            const v2f tv0 = bperm2(upA, u[5][0]);
            const v2f tv1 = bperm2(upA, u[5][1]);
            const v2f tv2 = bperm2(upA, u[5][2]);
            const v2f bv0 = bperm2(dnA, u[0][0]);
            const v2f bv1 = bperm2(dnA, u[0][1]);
            const v2f bv2 = bperm2(dnA, u[0][2]);
            // seam rows cross waves through LDS
            if (half == 0 && isBotTy) {         // new row 23 -> half1's top
                lds[bq][pib][1][c0 + 0] = u[5][0];
                lds[bq][pib][1][c0 + 1] = u[5][1];
                lds[bq][pib][1][c0 + 2] = u[5][2];
            }
            if (half == 1 && isTopTy) {         // new row 24 -> half0's bottom
                lds[bq][pib][2][c0 + 0] = u[0][0];
                lds[bq][pib][2][c0 + 1] = u[0][1];
                lds[bq][pib][2][c0 + 2] = u[0][2];
            }
            __syncthreads();
            v2f sT0, sT1, sT2, sB0, sB1, sB2;
            if (isTopTy) {
                sT0 = lds[bq][pib][topRow][c0 + 0];
                sT1 = lds[bq][pib][topRow][c0 + 1];
                sT2 = lds[bq][pib][topRow][c0 + 2];
            }
            if (isBotTy) {
                sB0 = lds[bq][pib][botRow][c0 + 0];
                sB1 = lds[bq][pib][botRow][c0 + 1];
                sB2 = lds[bq][pib][botRow][c0 + 2];
            }
            tH[0] = isTopTy ? sT0 : tv0;
            tH[1] = isTopTy ? sT1 : tv1;
            tH[2] = isTopTy ? sT2 : tv2;
            bH[0] = isBotTy ? sB0 : bv0;
            bH[1] = isBotTy ? sB1 : bv1;
            bH[2] = isBotTy ? sB2 : bv2;
        }
    }

    float* __restrict__ dstA = out + (size_t)(2 * pair) * 2304;
    float* __restrict__ dstB = dstA + 2304;
    #pragma unroll
    for (int k = 0; k < 6; ++k) {
        #pragma unroll
        for (int c = 0; c < 3; ++c) {
            int o = (g0 + k) * 48 + c0 + c;
            dstA[o] = u[k][c].x;
            dstB[o] = u[k][c].y;
        }
    }
}

extern "C" void kernel_launch(void* const* d_in, const int* in_sizes, int n_in,
                              void* d_out, int out_size, void* d_ws, size_t ws_size,
                              hipStream_t stream) {
    const float* u0 = (const float*)d_in[0];
    float* ws = (float*)d_ws;
    coeff_kernel<<<1, 64, 0, stream>>>(
        (const float*)d_in[1], (const float*)d_in[2], (const float*)d_in[3],
        (const float*)d_in[4], (const float*)d_in[5], (const float*)d_in[6],
        ws);
    pde_kernel<<<2048, 256, 0, stream>>>(u0, ws, (float*)d_out);
}